// Round 8
// baseline (2473.496 us; speedup 1.0000x reference)
//
#include <hip/hip_runtime.h>
#include <math.h>

#define TFULL 2049
#define TCTX  2048
#define Vm    50257

// LDS layout (A and R planes), per k-block kb:
//   off_shorts(kb, mt, kq, tokL, j) =
//     kb*1032 + mt*512 + kq*128 + ((tokL&12)|((tokL^kq)&3))*8 + j
// kb-stride 1032 shorts = 2064 B. Fragment read for lane (kq,mrow) =
// base + lane*16 bytes -> 1024 consecutive bytes per wave (conflict-free).
#define KBS 1032

typedef __attribute__((ext_vector_type(8))) short bf16x8;
typedef __attribute__((ext_vector_type(4))) short s16x4;
typedef __attribute__((ext_vector_type(4))) float f32x4;

__device__ __forceinline__ float wred64(float v){
  #pragma unroll
  for (int m = 1; m < 64; m <<= 1) v += __shfl_xor(v, m, 64);
  return v;
}
__device__ __forceinline__ short bf16_rn(float x){
  union { float f; unsigned u; } c; c.f = x;
  unsigned r = c.u + 0x7fff + ((c.u >> 16) & 1);
  return (short)(r >> 16);
}
__device__ __forceinline__ float bf16_f(short s){
  union { float f; unsigned u; } c; c.u = ((unsigned)(unsigned short)s) << 16;
  return c.f;
}

#define FMA4(ACC_, S_, W_)                         \
  (ACC_).x = fmaf((S_), (W_).x, (ACC_).x);         \
  (ACC_).y = fmaf((S_), (W_).y, (ACC_).y);         \
  (ACC_).z = fmaf((S_), (W_).z, (ACC_).z);         \
  (ACC_).w = fmaf((S_), (W_).w, (ACC_).w);

// --------------------------------------------- K0: folded scalars + gammaWg
__global__ void k0_setup(const float* __restrict__ gamma, const float* __restrict__ beta,
                         const float* __restrict__ Wg, float* __restrict__ scal){
  const int t = threadIdx.x;        // 512 threads
  float wg = Wg[t];
  float g  = gamma[t]*wg, bw = beta[t]*wg;
  scal[2 + t] = g;                  // gamma*Wg table
  g = wred64(g); bw = wred64(bw);
  __shared__ float ra[8], rb[8];
  if ((t & 63) == 0){ ra[t>>6] = g; rb[t>>6] = bw; }
  __syncthreads();
  if (t == 0){
    float G = 0.f, Bw = 0.f;
    #pragma unroll
    for (int i = 0; i < 8; ++i){ G += ra[i]; Bw += rb[i]; }
    scal[0] = G; scal[1] = Bw;
  }
}

// ---------------------- K0b: split W into bf16 hi/lo, packed B-fragment order
__global__ __launch_bounds__(256) void kpack(const float* __restrict__ W, int N, int KB,
                                             short* __restrict__ hi, short* __restrict__ lo){
  int i = blockIdx.x*256 + threadIdx.x;   // over KB*N*4 (kb,n,kq)
  if (i >= KB*N*4) return;
  int kq = i & 3;
  int n  = (i >> 2) % N;
  int kb = i / (N*4);
  const float* src = W + (kb*32 + kq*8)*N + n;
  bf16x8 h8, l8;
  #pragma unroll
  for (int j = 0; j < 8; ++j){
    float w = src[j*N];
    short h = bf16_rn(w);
    h8[j] = h;
    l8[j] = bf16_rn(w - bf16_f(h));
  }
  *(bf16x8*)(hi + i*8) = h8;
  *(bf16x8*)(lo + i*8) = l8;
}

// ------------------------------------------------- K1: fused FF+LN+gate tile
// Round-8: round-6 design (full-K-resident A, single stage, barrier-free g1,
// VGPR cap 256) with BOUNDED unrolls (kbr x4, kb x2) to cap straight-line
// codegen size — the only structural novelty in the twice-unbenched round-6.
__global__ __launch_bounds__(512, 2) void k1_main(
    const int*   __restrict__ seq,   const float* __restrict__ temp,
    const float* __restrict__ gumbel,const float* __restrict__ embed,
    const short* __restrict__ W1h,   const short* __restrict__ W1l,
    const float* __restrict__ b1,
    const short* __restrict__ W2h,   const short* __restrict__ W2l,
    const float* __restrict__ b2,
    const float* __restrict__ gamma, const float* __restrict__ beta,
    const float* __restrict__ bg,
    const float* __restrict__ scal,
    float* __restrict__ pert, float* __restrict__ qh)
{
  __shared__ __align__(16) short Ah[16*KBS];     // 33KB (full K)
  __shared__ __align__(16) short Al[16*KBS];     // 33KB
  __shared__ __align__(16) short Rbuf[2*8*KBS];  // 33KB: Rh + Rl
  __shared__ float Xq[512];      // x of the qh token (if any)
  __shared__ int   srow[32];
  __shared__ float redS1[256], redS2[256], redSG[256];  // 32 tok x 8 wv
  __shared__ float redMu[32], redRs[32];

  short* Rh = Rbuf;
  short* Rl = Rbuf + 8*KBS;

  const int t    = threadIdx.x;
  const int tile = blockIdx.x;
  const int lane = t & 63;
  const int wv   = t >> 6;        // 0..7
  const int mrow = lane & 15;     // A-frag m / C col / B-frag n
  const int kq   = lane >> 4;     // k-quad
  const int crow0 = kq*4;         // C rows

  // per-lane fragment-read offset within a (kb, mt) plane (shorts):
  const int lane_sw = kq*128 + ((mrow & 12) | ((mrow ^ kq) & 3))*8;

  if (t < 32) srow[t] = seq[tile*32 + t];
  __syncthreads();

  const f32x4* __restrict__ embv = (const f32x4*)embed;

  // ---- stage full K of the 32 embed rows -> A planes (ONCE) ----
  #pragma unroll
  for (int k = 0; k < 8; ++k){
    int idx = k*512 + t;                 // 4096 float4 = 32 tok x 128 c4
    int tok = idx >> 7, c4 = idx & 127;
    f32x4 v = embv[srow[tok]*128 + c4];
    int kbr = c4 >> 3, kqw = (c4 >> 1) & 3, j0 = (c4 & 1)*4;
    int tokL = tok & 15, mt = tok >> 4;
    int base = kbr*KBS + mt*512 + kqw*128
             + ((tokL & 12) | ((tokL ^ kqw) & 3))*8 + j0;
    short h0 = bf16_rn(v[0]), h1 = bf16_rn(v[1]), h2 = bf16_rn(v[2]), h3 = bf16_rn(v[3]);
    *(s16x4*)(Ah + base) = (s16x4){h0, h1, h2, h3};
    *(s16x4*)(Al + base) = (s16x4){ bf16_rn(v[0] - bf16_f(h0)),
                                    bf16_rn(v[1] - bf16_f(h1)),
                                    bf16_rn(v[2] - bf16_f(h2)),
                                    bf16_rn(v[3] - bf16_f(h3)) };
  }
  __syncthreads();

  f32x4 ff[4][2];  // [nt][mt]; d = wv*64 + nt*16 + mrow, tok = mt*16 + kq*4 + r
  #pragma unroll
  for (int i = 0; i < 4; ++i)
    #pragma unroll
    for (int j = 0; j < 2; ++j) ff[i][j] = (f32x4){0.f,0.f,0.f,0.f};

  int boff2[4];
  #pragma unroll
  for (int nt = 0; nt < 4; ++nt)
    boff2[nt] = (wv*64 + nt*16 + mrow)*32 + kq*8;   // W2 lane offset

  #pragma unroll 1
  for (int ch = 0; ch < 4; ++ch){
    // ---------- GEMM1: a[32 x 256chunk], full K, no barriers ----------
    f32x4 acc[2][2];   // [nt][mt]
    #pragma unroll
    for (int i = 0; i < 2; ++i)
      #pragma unroll
      for (int j = 0; j < 2; ++j) acc[i][j] = (f32x4){0.f,0.f,0.f,0.f};

    int boff1[2];
    #pragma unroll
    for (int nt = 0; nt < 2; ++nt)
      boff1[nt] = (ch*256 + wv*32 + nt*16 + mrow)*32 + kq*8;  // W1 lane offset

    #pragma unroll 4
    for (int kbr = 0; kbr < 16; ++kbr){
      bf16x8 ah0 = *(const bf16x8*)(Ah + kbr*KBS + lane_sw);
      bf16x8 al0 = *(const bf16x8*)(Al + kbr*KBS + lane_sw);
      bf16x8 ah1 = *(const bf16x8*)(Ah + kbr*KBS + 512 + lane_sw);
      bf16x8 al1 = *(const bf16x8*)(Al + kbr*KBS + 512 + lane_sw);
      #pragma unroll
      for (int nt = 0; nt < 2; ++nt){
        bf16x8 bh = *(const bf16x8*)(W1h + kbr*32768 + boff1[nt]);
        bf16x8 bl = *(const bf16x8*)(W1l + kbr*32768 + boff1[nt]);
        acc[nt][0] = __builtin_amdgcn_mfma_f32_16x16x32_bf16(ah0, bh, acc[nt][0], 0,0,0);
        acc[nt][0] = __builtin_amdgcn_mfma_f32_16x16x32_bf16(al0, bh, acc[nt][0], 0,0,0);
        acc[nt][0] = __builtin_amdgcn_mfma_f32_16x16x32_bf16(ah0, bl, acc[nt][0], 0,0,0);
        acc[nt][1] = __builtin_amdgcn_mfma_f32_16x16x32_bf16(ah1, bh, acc[nt][1], 0,0,0);
        acc[nt][1] = __builtin_amdgcn_mfma_f32_16x16x32_bf16(al1, bh, acc[nt][1], 0,0,0);
        acc[nt][1] = __builtin_amdgcn_mfma_f32_16x16x32_bf16(ah1, bl, acc[nt][1], 0,0,0);
      }
    }

    __syncthreads();   // gemm2(ch-1) done reading R

    // relu + bias -> R planes (fragment order for GEMM2)
    #pragma unroll
    for (int nt = 0; nt < 2; ++nt){
      int jcol = wv*32 + nt*16 + mrow;        // 0..255 chunk-local
      float bb = b1[ch*256 + jcol];
      int kb2 = jcol >> 5, kq2 = (jcol >> 3) & 3, j2 = jcol & 7;
      int rbase = kb2*KBS + kq2*128 + j2;
      #pragma unroll
      for (int mt = 0; mt < 2; ++mt){
        #pragma unroll
        for (int r = 0; r < 4; ++r){
          int tokL = crow0 + r;
          int off = rbase + mt*512 + ((tokL & 12) | ((tokL ^ kq2) & 3))*8;
          float a = fmaxf(acc[nt][mt][r] + bb, 0.f);
          short h = bf16_rn(a);
          Rh[off] = h;
          Rl[off] = bf16_rn(a - bf16_f(h));
        }
      }
    }
    __syncthreads();

    // ---------- GEMM2 partial: ff += relu . W2[chunk rows] ----------
    {
      const short* w2hB = W2h + ch*131072;   // ch*8*16384
      const short* w2lB = W2l + ch*131072;
      #pragma unroll 2
      for (int kb = 0; kb < 8; ++kb){
        bf16x8 rh0 = *(const bf16x8*)(Rh + kb*KBS + lane_sw);
        bf16x8 rl0 = *(const bf16x8*)(Rl + kb*KBS + lane_sw);
        bf16x8 rh1 = *(const bf16x8*)(Rh + kb*KBS + 512 + lane_sw);
        bf16x8 rl1 = *(const bf16x8*)(Rl + kb*KBS + 512 + lane_sw);
        #pragma unroll
        for (int nt = 0; nt < 4; ++nt){
          bf16x8 bh = *(const bf16x8*)(w2hB + kb*16384 + boff2[nt]);
          bf16x8 bl = *(const bf16x8*)(w2lB + kb*16384 + boff2[nt]);
          ff[nt][0] = __builtin_amdgcn_mfma_f32_16x16x32_bf16(rh0, bh, ff[nt][0], 0,0,0);
          ff[nt][0] = __builtin_amdgcn_mfma_f32_16x16x32_bf16(rl0, bh, ff[nt][0], 0,0,0);
          ff[nt][0] = __builtin_amdgcn_mfma_f32_16x16x32_bf16(rh0, bl, ff[nt][0], 0,0,0);
          ff[nt][1] = __builtin_amdgcn_mfma_f32_16x16x32_bf16(rh1, bh, ff[nt][1], 0,0,0);
          ff[nt][1] = __builtin_amdgcn_mfma_f32_16x16x32_bf16(rl1, bh, ff[nt][1], 0,0,0);
          ff[nt][1] = __builtin_amdgcn_mfma_f32_16x16x32_bf16(rh1, bl, ff[nt][1], 0,0,0);
        }
      }
    }
  }

  // ---------------- epilogue (A fully resident: no re-gather) ----------------
  const float G1 = scal[0], BW = scal[1];
  const float* gWg = scal + 2;
  const float bgv  = bg[0];
  const float invT = 1.0f / temp[0];
  int rem  = (tile*32) % 2049;
  int qtok = 2048 - rem;          // valid if < 32

  float ps1[2][4], ps2[2][4], psg[2][4];   // [mt][r]
  #pragma unroll
  for (int mt = 0; mt < 2; ++mt)
    #pragma unroll
    for (int r = 0; r < 4; ++r){ ps1[mt][r]=0.f; ps2[mt][r]=0.f; psg[mt][r]=0.f; }

  #pragma unroll
  for (int nt = 0; nt < 4; ++nt){
    int d = wv*64 + nt*16 + mrow;
    float b2v = b2[d];
    float gw  = gWg[d];
    int kb  = d >> 5, kq2 = (d >> 3) & 3, jj = d & 7;
    int abase = kb*KBS + kq2*128 + jj;
    #pragma unroll
    for (int mt = 0; mt < 2; ++mt){
      #pragma unroll
      for (int r = 0; r < 4; ++r){
        int tokL = crow0 + r;
        int tok  = mt*16 + tokL;
        int off  = abase + mt*512 + ((tokL & 12) | ((tokL ^ kq2) & 3))*8;
        float h = bf16_f(Ah[off]) + bf16_f(Al[off]);
        float x = h + ff[nt][mt][r] + b2v;
        ps1[mt][r] += x;
        ps2[mt][r] = fmaf(x, x, ps2[mt][r]);
        psg[mt][r] = fmaf(x, gw, psg[mt][r]);
        if (tok == qtok) Xq[d] = x;
      }
    }
  }
  // reduce over mrow (lane bits 0..3)
  #pragma unroll
  for (int mt = 0; mt < 2; ++mt){
    #pragma unroll
    for (int r = 0; r < 4; ++r){
      float a = ps1[mt][r], b = ps2[mt][r], c = psg[mt][r];
      #pragma unroll
      for (int m = 1; m < 16; m <<= 1){
        a += __shfl_xor(a, m, 64);
        b += __shfl_xor(b, m, 64);
        c += __shfl_xor(c, m, 64);
      }
      if (mrow == 0){
        int tok = mt*16 + crow0 + r;
        redS1[tok*8 + wv] = a;
        redS2[tok*8 + wv] = b;
        redSG[tok*8 + wv] = c;
      }
    }
  }
  __syncthreads();

  if (t < 32){
    float S1 = 0.f, S2 = 0.f, SG = 0.f;
    #pragma unroll
    for (int w = 0; w < 8; ++w){
      S1 += redS1[t*8 + w];
      S2 += redS2[t*8 + w];
      SG += redSG[t*8 + w];
    }
    float mu  = S1 * (1.f/512.f);
    float var = S2 * (1.f/512.f) - mu*mu;
    float rs  = rsqrtf(var + 1e-5f);
    redMu[t] = mu; redRs[t] = rs;
    int id  = tile*32 + t;
    int b   = id / 2049;
    int pos = id - b*2049;
    if (pos < TCTX){
      float gate = rs*(SG - mu*G1) + BW + bgv;
      float pv = (gate + __builtin_nontemporal_load(gumbel + b*TCTX + pos)) * invT;
      __builtin_nontemporal_store(pv, pert + b*TCTX + pos);
    }
  }
  __syncthreads();

  if (qtok < 32 && t < 256){
    int id = tile*32 + qtok;
    int b  = id / 2049;
    float mu = redMu[qtok], rs = redRs[qtok];
    int d = t*2;
    qh[b*512 + d]     = (Xq[d]  -mu)*rs*gamma[d]   + beta[d];
    qh[b*512 + d + 1] = (Xq[d+1]-mu)*rs*gamma[d+1] + beta[d+1];
  }
}

// ---------------------------------------------------------------- K2: top-3
__global__ __launch_bounds__(256) void k2_topk(const float* __restrict__ pert,
                                               int* __restrict__ idxw){
  __shared__ float v[2048];
  __shared__ float wvv[256];
  __shared__ int   wii[256];
  const int b = blockIdx.x, t = threadIdx.x;
  for (int i = t; i < 2048; i += 256) v[i] = pert[b*TCTX + i];
  __syncthreads();
  for (int r = 0; r < 3; ++r){
    float best = -INFINITY; int bi = 1<<30;
    for (int i = t; i < 2048; i += 256){
      float x = v[i];
      if (x > best || (x == best && i < bi)){ best = x; bi = i; }
    }
    wvv[t] = best; wii[t] = bi;
    __syncthreads();
    for (int s = 128; s > 0; s >>= 1){
      if (t < s){
        float ov = wvv[t+s]; int oi = wii[t+s];
        if (ov > wvv[t] || (ov == wvv[t] && oi < wii[t])){ wvv[t] = ov; wii[t] = oi; }
      }
      __syncthreads();
    }
    if (t == 0){ idxw[b*3 + r] = wii[0]; v[wii[0]] = -INFINITY; }
    __syncthreads();
  }
}

// -------------------------------------- K3: recompute hiddens for top-3 rows
__global__ __launch_bounds__(256) void k3_rows(const int* __restrict__ seq,
    const float* __restrict__ embed, const float* __restrict__ W1, const float* __restrict__ b1,
    const float* __restrict__ W2,    const float* __restrict__ b2,
    const float* __restrict__ gamma, const float* __restrict__ beta,
    const int* __restrict__ idxw, float* __restrict__ memr)
{
  __shared__ float hs[3*512];
  __shared__ float rbuf[3*1024];
  __shared__ float red1[12], red2[12];
  const int t  = threadIdx.x;
  const int b  = blockIdx.x;
  const int wv = t >> 6;
  #pragma unroll
  for (int kk = 0; kk < 3; ++kk){
    int pos = idxw[b*3 + kk];
    int row = seq[b*TFULL + pos];
    ((float2*)(hs + kk*512))[t] = ((const float2*)(embed + row*512))[t];
  }
  __syncthreads();
  const float4* W1v = (const float4*)W1;
  float4 a0 = make_float4(0,0,0,0), a1 = a0, a2 = a0;
  #pragma unroll 2
  for (int d = 0; d < 512; ++d){
    float4 wq = W1v[d*256 + t];
    float h0 = hs[d], h1 = hs[512+d], h2 = hs[1024+d];
    FMA4(a0, h0, wq); FMA4(a1, h1, wq); FMA4(a2, h2, wq);
  }
  float4 bq = ((const float4*)b1)[t];
  float4 r0, r1, r2;
  r0.x = fmaxf(a0.x+bq.x,0.f); r0.y = fmaxf(a0.y+bq.y,0.f);
  r0.z = fmaxf(a0.z+bq.z,0.f); r0.w = fmaxf(a0.w+bq.w,0.f);
  r1.x = fmaxf(a1.x+bq.x,0.f); r1.y = fmaxf(a1.y+bq.y,0.f);
  r1.z = fmaxf(a1.z+bq.z,0.f); r1.w = fmaxf(a1.w+bq.w,0.f);
  r2.x = fmaxf(a2.x+bq.x,0.f); r2.y = fmaxf(a2.y+bq.y,0.f);
  r2.z = fmaxf(a2.z+bq.z,0.f); r2.w = fmaxf(a2.w+bq.w,0.f);
  ((float4*)rbuf)[t]          = r0;
  ((float4*)(rbuf+1024))[t]   = r1;
  ((float4*)(rbuf+2048))[t]   = r2;
  __syncthreads();
  const float2* W2v2 = (const float2*)W2;
  float f0x=0.f,f0y=0.f,f1x=0.f,f1y=0.f,f2x=0.f,f2y=0.f;
  #pragma unroll 2
  for (int j = 0; j < 1024; ++j){
    float2 wq = W2v2[j*256 + t];
    float q0 = rbuf[j], q1 = rbuf[1024+j], q2 = rbuf[2048+j];
    f0x = fmaf(q0, wq.x, f0x); f0y = fmaf(q0, wq.y, f0y);
    f1x = fmaf(q1, wq.x, f1x); f1y = fmaf(q1, wq.y, f1y);
    f2x = fmaf(q2, wq.x, f2x); f2y = fmaf(q2, wq.y, f2y);
  }
  float2 b2q = ((const float2*)b2)[t];
  const int dd = t*2;
  float2 hx0 = ((float2*)hs)[t];
  float2 hx1 = ((float2*)(hs+512))[t];
  float2 hx2 = ((float2*)(hs+1024))[t];
  float x00 = hx0.x + f0x + b2q.x, x01 = hx0.y + f0y + b2q.y;
  float x10 = hx1.x + f1x + b2q.x, x11 = hx1.y + f1y + b2q.y;
  float x20 = hx2.x + f2x + b2q.x, x21 = hx2.y + f2y + b2q.y;
  float s10 = wred64(x00 + x01), s20 = wred64(x00*x00 + x01*x01);
  float s11 = wred64(x10 + x11), s21 = wred64(x10*x10 + x11*x11);
  float s12 = wred64(x20 + x21), s22 = wred64(x20*x20 + x21*x21);
  if ((t & 63) == 0){
    red1[0*4+wv] = s10; red2[0*4+wv] = s20;
    red1[1*4+wv] = s11; red2[1*4+wv] = s21;
    red1[2*4+wv] = s12; red2[2*4+wv] = s22;
  }
  __syncthreads();
  float gx = gamma[dd], gy = gamma[dd+1], bx = beta[dd], by = beta[dd+1];
  #pragma unroll
  for (int kk = 0; kk < 3; ++kk){
    float S1 = red1[kk*4+0]+red1[kk*4+1]+red1[kk*4+2]+red1[kk*4+3];
    float S2 = red2[kk*4+0]+red2[kk*4+1]+red2[kk*4+2]+red2[kk*4+3];
    float mu  = S1*(1.f/512.f);
    float var = S2*(1.f/512.f) - mu*mu;
    float rs  = rsqrtf(var + 1e-5f);
    float x0 = (kk==0) ? x00 : (kk==1) ? x10 : x20;
    float x1 = (kk==0) ? x01 : (kk==1) ? x11 : x21;
    memr[(b*3+kk)*512 + dd]     = (x0-mu)*rs*gx + bx;
    memr[(b*3+kk)*512 + dd + 1] = (x1-mu)*rs*gy + by;
  }
}

// ------------------------------------------- K4: q, slot attention, ctx (T)
__global__ __launch_bounds__(256) void k4_attn(const float* __restrict__ qh,
    const float* __restrict__ Wr, const float* __restrict__ br,
    const float* __restrict__ memr, float* __restrict__ ctxT)
{
  __shared__ float hq[512];
  __shared__ float red[12];
  const int t = threadIdx.x, b = blockIdx.x;
  ((float2*)hq)[t] = ((const float2*)(qh + b*512))[t];
  __syncthreads();
  const float2* Wrv = (const float2*)Wr;
  float qx = 0.f, qy = 0.f;
  #pragma unroll 4
  for (int d = 0; d < 512; ++d){
    float hb = hq[d];
    float2 wq = Wrv[d*256 + t];
    qx = fmaf(hb, wq.x, qx); qy = fmaf(hb, wq.y, qy);
  }
  float2 brq = ((const float2*)br)[t];
  qx += brq.x; qy += brq.y;
  const int dd = t*2;
  const float* m0 = memr + (b*3+0)*512;
  const float* m1 = memr + (b*3+1)*512;
  const float* m2 = memr + (b*3+2)*512;
  float p0 = wred64(qx*m0[dd] + qy*m0[dd+1]);
  float p1 = wred64(qx*m1[dd] + qy*m1[dd+1]);
  float p2 = wred64(qx*m2[dd] + qy*m2[dd+1]);
  if ((t & 63) == 0){ int w = t>>6; red[w*3+0]=p0; red[w*3+1]=p1; red[w*3+2]=p2; }
  __syncthreads();
  float s0 = red[0]+red[3]+red[6]+red[9];
  float s1 = red[1]+red[4]+red[7]+red[10];
  float s2 = red[2]+red[5]+red[8]+red[11];
  float m  = fmaxf(fmaxf(s0, s1), fmaxf(s2, 0.f));
  float e0 = expf(s0-m), e1 = expf(s1-m), e2 = expf(s2-m);
  float den = e0 + e1 + e2 + 13.f*expf(-m);   // 13 empty slots
  float a0 = e0/den, a1 = e1/den, a2 = e2/den;
  float c0 = a0*m0[dd]   + a1*m1[dd]   + a2*m2[dd];
  float c1 = a0*m0[dd+1] + a1*m1[dd+1] + a2*m2[dd+1];
  ctxT[dd*64 + b]     = c0;
  ctxT[(dd+1)*64 + b] = c1;
}

// ----------------------------------------------------- K5: out = ctx@Wo + bo
__global__ __launch_bounds__(256) void k5_out(const float* __restrict__ ctxT,
    const float* __restrict__ Wo, const float* __restrict__ bo,
    float* __restrict__ out)
{
  const int v  = blockIdx.x*256 + threadIdx.x;
  const int vc = v < Vm ? v : Vm-1;
  float acc[64];
  #pragma unroll
  for (int b = 0; b < 64; ++b) acc[b] = 0.f;
  for (int d = 0; d < 512; ++d){
    float w = Wo[d*Vm + vc];
    const float* c = ctxT + d*64;
    #pragma unroll
    for (int b = 0; b < 64; ++b) acc[b] = fmaf(c[b], w, acc[b]);
  }
  if (v < Vm){
    float bb = bo[v];
    #pragma unroll
    for (int b = 0; b < 64; ++b) out[b*Vm + v] = acc[b] + bb;
  }
}

extern "C" void kernel_launch(void* const* d_in, const int* in_sizes, int n_in,
                              void* d_out, int out_size, void* d_ws, size_t ws_size,
                              hipStream_t stream){
  (void)in_sizes; (void)n_in; (void)out_size; (void)ws_size;
  const int*   seq   = (const int*)d_in[0];
  const float* temp  = (const float*)d_in[1];
  const float* gum   = (const float*)d_in[2];
  const float* embed = (const float*)d_in[3];
  const float* W1    = (const float*)d_in[4];
  const float* b1    = (const float*)d_in[5];
  const float* W2    = (const float*)d_in[6];
  const float* b2    = (const float*)d_in[7];
  const float* gamma = (const float*)d_in[8];
  const float* beta  = (const float*)d_in[9];
  const float* Wg    = (const float*)d_in[10];
  const float* bg    = (const float*)d_in[11];
  const float* Wr    = (const float*)d_in[12];
  const float* br    = (const float*)d_in[13];
  const float* Wo    = (const float*)d_in[14];
  const float* bo    = (const float*)d_in[15];
  float* out = (float*)d_out;

  float* wsf  = (float*)d_ws;
  float* pert = wsf;                    // 131072
  float* qh   = wsf + 131072;           // 32768
  float* memr = wsf + 163840;           // 98304
  float* ctxT = wsf + 262144;           // 32768
  float* scal = wsf + 294912;           // 1024 (uses 514)
  int*   idxw = (int*)(wsf + 295936);   // 256 ints
  short* W1h  = (short*)(wsf + 296192); // 512*1024 shorts each plane
  short* W1l  = W1h + 512*1024;
  short* W2h  = W1l + 512*1024;
  short* W2l  = W2h + 1024*512;

  k0_setup<<<1, 512, 0, stream>>>(gamma, beta, Wg, scal);
  kpack<<<256, 256, 0, stream>>>(W1, 1024, 16, W1h, W1l);
  kpack<<<256, 256, 0, stream>>>(W2, 512, 32, W2h, W2l);
  k1_main<<<4098, 512, 0, stream>>>(seq, temp, gum, embed, W1h, W1l, b1,
                                    W2h, W2l, b2, gamma, beta, bg, scal, pert, qh);
  k2_topk<<<64, 256, 0, stream>>>(pert, idxw);
  k3_rows<<<64, 256, 0, stream>>>(seq, embed, W1, b1, W2, b2, gamma, beta, idxw, memr);
  k4_attn<<<64, 256, 0, stream>>>(qh, Wr, br, memr, ctxT);
  k5_out<<<197, 256, 0, stream>>>(ctxT, Wo, bo, out);
}

// Round 9
// 1893.492 us; speedup vs baseline: 1.3063x; 1.3063x over previous
//
#include <hip/hip_runtime.h>
#include <math.h>

#define TFULL 2049
#define TCTX  2048
#define Vm    50257

// LDS layout (A and R planes), per k-block kb:
//   off_shorts(kb, mt, kq, tokL, j) =
//     kb*1032 + mt*512 + kq*128 + ((tokL&12)|((tokL^kq)&3))*8 + j
// kb-stride 1032 shorts = 2064 B. Fragment read for lane (kq,mrow) =
// base + lane*16 bytes -> 1024 consecutive bytes per wave (conflict-free).
#define KBS 1032

typedef __attribute__((ext_vector_type(8))) short bf16x8;
typedef __attribute__((ext_vector_type(4))) short s16x4;
typedef __attribute__((ext_vector_type(4))) float f32x4;

__device__ __forceinline__ float wred64(float v){
  #pragma unroll
  for (int m = 1; m < 64; m <<= 1) v += __shfl_xor(v, m, 64);
  return v;
}
__device__ __forceinline__ short bf16_rn(float x){
  union { float f; unsigned u; } c; c.f = x;
  unsigned r = c.u + 0x7fff + ((c.u >> 16) & 1);
  return (short)(r >> 16);
}
__device__ __forceinline__ float bf16_f(short s){
  union { float f; unsigned u; } c; c.u = ((unsigned)(unsigned short)s) << 16;
  return c.f;
}
// Opaque 16B global load: compiler cannot fold/reorder it; completion is
// managed manually with counted s_waitcnt vmcnt(N).
__device__ __forceinline__ bf16x8 gld16(const short* p){
  bf16x8 r;
  asm volatile("global_load_dwordx4 %0, %1, off" : "=v"(r) : "v"(p));
  return r;
}

#define FMA4(ACC_, S_, W_)                         \
  (ACC_).x = fmaf((S_), (W_).x, (ACC_).x);         \
  (ACC_).y = fmaf((S_), (W_).y, (ACC_).y);         \
  (ACC_).z = fmaf((S_), (W_).z, (ACC_).z);         \
  (ACC_).w = fmaf((S_), (W_).w, (ACC_).w);

// --------------------------------------------- K0: folded scalars + gammaWg
__global__ void k0_setup(const float* __restrict__ gamma, const float* __restrict__ beta,
                         const float* __restrict__ Wg, float* __restrict__ scal){
  const int t = threadIdx.x;        // 512 threads
  float wg = Wg[t];
  float g  = gamma[t]*wg, bw = beta[t]*wg;
  scal[2 + t] = g;                  // gamma*Wg table
  g = wred64(g); bw = wred64(bw);
  __shared__ float ra[8], rb[8];
  if ((t & 63) == 0){ ra[t>>6] = g; rb[t>>6] = bw; }
  __syncthreads();
  if (t == 0){
    float G = 0.f, Bw = 0.f;
    #pragma unroll
    for (int i = 0; i < 8; ++i){ G += ra[i]; Bw += rb[i]; }
    scal[0] = G; scal[1] = Bw;
  }
}

// ---------------------- K0b: split W into bf16 hi/lo, packed B-fragment order
__global__ __launch_bounds__(256) void kpack(const float* __restrict__ W, int N, int KB,
                                             short* __restrict__ hi, short* __restrict__ lo){
  int i = blockIdx.x*256 + threadIdx.x;   // over KB*N*4 (kb,n,kq)
  if (i >= KB*N*4) return;
  int kq = i & 3;
  int n  = (i >> 2) % N;
  int kb = i / (N*4);
  const float* src = W + (kb*32 + kq*8)*N + n;
  bf16x8 h8, l8;
  #pragma unroll
  for (int j = 0; j < 8; ++j){
    float w = src[j*N];
    short h = bf16_rn(w);
    h8[j] = h;
    l8[j] = bf16_rn(w - bf16_f(h));
  }
  *(bf16x8*)(hi + i*8) = h8;
  *(bf16x8*)(lo + i*8) = l8;
}

// ------------------------------------------------- K1: fused FF+LN+gate tile
// Round-9: r8 config (full-K-resident A, 1 blk/CU, conflict-free layout) +
// manual counted-vmcnt B-fragment pipeline (depth-3 in GEMM1, depth-2 in
// GEMM2) via opaque asm loads. A ds_reads hoisted above the vmcnt wait so
// LDS latency hides under it. Arithmetic order bit-identical to r8.
__global__ __launch_bounds__(512, 2) void k1_main(
    const int*   __restrict__ seq,   const float* __restrict__ temp,
    const float* __restrict__ gumbel,const float* __restrict__ embed,
    const short* __restrict__ W1h,   const short* __restrict__ W1l,
    const float* __restrict__ b1,
    const short* __restrict__ W2h,   const short* __restrict__ W2l,
    const float* __restrict__ b2,
    const float* __restrict__ gamma, const float* __restrict__ beta,
    const float* __restrict__ bg,
    const float* __restrict__ scal,
    float* __restrict__ pert, float* __restrict__ qh)
{
  __shared__ __align__(16) short Ah[16*KBS];     // 33KB (full K)
  __shared__ __align__(16) short Al[16*KBS];     // 33KB
  __shared__ __align__(16) short Rbuf[2*8*KBS];  // 33KB: Rh + Rl
  __shared__ float Xq[512];      // x of the qh token (if any)
  __shared__ int   srow[32];
  __shared__ float redS1[256], redS2[256], redSG[256];  // 32 tok x 8 wv
  __shared__ float redMu[32], redRs[32];

  short* Rh = Rbuf;
  short* Rl = Rbuf + 8*KBS;

  const int t    = threadIdx.x;
  const int tile = blockIdx.x;
  const int lane = t & 63;
  const int wv   = t >> 6;        // 0..7
  const int mrow = lane & 15;     // A-frag m / C col / B-frag n
  const int kq   = lane >> 4;     // k-quad
  const int crow0 = kq*4;         // C rows

  // per-lane fragment-read offset within a (kb, mt) plane (shorts):
  const int lane_sw = kq*128 + ((mrow & 12) | ((mrow ^ kq) & 3))*8;

  if (t < 32) srow[t] = seq[tile*32 + t];
  __syncthreads();

  const f32x4* __restrict__ embv = (const f32x4*)embed;

  // ---- stage full K of the 32 embed rows -> A planes (ONCE) ----
  #pragma unroll
  for (int k = 0; k < 8; ++k){
    int idx = k*512 + t;                 // 4096 float4 = 32 tok x 128 c4
    int tok = idx >> 7, c4 = idx & 127;
    f32x4 v = embv[srow[tok]*128 + c4];
    int kbr = c4 >> 3, kqw = (c4 >> 1) & 3, j0 = (c4 & 1)*4;
    int tokL = tok & 15, mt = tok >> 4;
    int base = kbr*KBS + mt*512 + kqw*128
             + ((tokL & 12) | ((tokL ^ kqw) & 3))*8 + j0;
    short h0 = bf16_rn(v[0]), h1 = bf16_rn(v[1]), h2 = bf16_rn(v[2]), h3 = bf16_rn(v[3]);
    *(s16x4*)(Ah + base) = (s16x4){h0, h1, h2, h3};
    *(s16x4*)(Al + base) = (s16x4){ bf16_rn(v[0] - bf16_f(h0)),
                                    bf16_rn(v[1] - bf16_f(h1)),
                                    bf16_rn(v[2] - bf16_f(h2)),
                                    bf16_rn(v[3] - bf16_f(h3)) };
  }
  __syncthreads();

  f32x4 ff[4][2];  // [nt][mt]; d = wv*64 + nt*16 + mrow, tok = mt*16 + kq*4 + r
  #pragma unroll
  for (int i = 0; i < 4; ++i)
    #pragma unroll
    for (int j = 0; j < 2; ++j) ff[i][j] = (f32x4){0.f,0.f,0.f,0.f};

  int boff2[4];
  #pragma unroll
  for (int nt = 0; nt < 4; ++nt)
    boff2[nt] = (wv*64 + nt*16 + mrow)*32 + kq*8;   // W2 lane offset

  #pragma unroll 1
  for (int ch = 0; ch < 4; ++ch){
    // ---------- GEMM1: a[32 x 256chunk], full K, counted-vmcnt pipeline ----------
    f32x4 acc[2][2];   // [nt][mt]
    #pragma unroll
    for (int i = 0; i < 2; ++i)
      #pragma unroll
      for (int j = 0; j < 2; ++j) acc[i][j] = (f32x4){0.f,0.f,0.f,0.f};

    int boff1[2];
    #pragma unroll
    for (int nt = 0; nt < 2; ++nt)
      boff1[nt] = (ch*256 + wv*32 + nt*16 + mrow)*32 + kq*8;  // W1 lane offset

    {
      const short* pH0 = W1h + boff1[0];
      const short* pL0 = W1l + boff1[0];
      const short* pH1 = W1h + boff1[1];
      const short* pL1 = W1l + boff1[1];
      bf16x8 Bh[4][2], Bl[4][2];
      // issue one k-block's 4 B-fragment loads (set S) into buffer S&3
      #define G1I(S) { Bh[(S)&3][0] = gld16(pH0 + (S)*32768); \
                       Bl[(S)&3][0] = gld16(pL0 + (S)*32768); \
                       Bh[(S)&3][1] = gld16(pH1 + (S)*32768); \
                       Bl[(S)&3][1] = gld16(pL1 + (S)*32768); }
      G1I(0) G1I(1) G1I(2)               // depth-3 prologue: 12 loads in flight
      #pragma unroll
      for (int kbr = 0; kbr < 16; ++kbr){
        // A ds_reads first: their latency hides under the vmcnt wait below
        bf16x8 ah0 = *(const bf16x8*)(Ah + kbr*KBS + lane_sw);
        bf16x8 al0 = *(const bf16x8*)(Al + kbr*KBS + lane_sw);
        bf16x8 ah1 = *(const bf16x8*)(Ah + kbr*KBS + 512 + lane_sw);
        bf16x8 al1 = *(const bf16x8*)(Al + kbr*KBS + 512 + lane_sw);
        if (kbr < 13) G1I(kbr + 3)       // keep 3 sets (12 loads) in flight
        // exact counted wait: set kbr must be complete
        if      (kbr < 13)  asm volatile("s_waitcnt vmcnt(12)");
        else if (kbr == 13) asm volatile("s_waitcnt vmcnt(8)");
        else if (kbr == 14) asm volatile("s_waitcnt vmcnt(4)");
        else                asm volatile("s_waitcnt vmcnt(0)");
        __builtin_amdgcn_sched_barrier(0);
        const int s = kbr & 3;           // compile-time (full unroll)
        #pragma unroll
        for (int nt = 0; nt < 2; ++nt){
          acc[nt][0] = __builtin_amdgcn_mfma_f32_16x16x32_bf16(ah0, Bh[s][nt], acc[nt][0], 0,0,0);
          acc[nt][0] = __builtin_amdgcn_mfma_f32_16x16x32_bf16(al0, Bh[s][nt], acc[nt][0], 0,0,0);
          acc[nt][0] = __builtin_amdgcn_mfma_f32_16x16x32_bf16(ah0, Bl[s][nt], acc[nt][0], 0,0,0);
          acc[nt][1] = __builtin_amdgcn_mfma_f32_16x16x32_bf16(ah1, Bh[s][nt], acc[nt][1], 0,0,0);
          acc[nt][1] = __builtin_amdgcn_mfma_f32_16x16x32_bf16(al1, Bh[s][nt], acc[nt][1], 0,0,0);
          acc[nt][1] = __builtin_amdgcn_mfma_f32_16x16x32_bf16(ah1, Bl[s][nt], acc[nt][1], 0,0,0);
        }
      }
      #undef G1I
    }

    __syncthreads();   // gemm2(ch-1) done reading R

    // relu + bias -> R planes (fragment order for GEMM2)
    #pragma unroll
    for (int nt = 0; nt < 2; ++nt){
      int jcol = wv*32 + nt*16 + mrow;        // 0..255 chunk-local
      float bb = b1[ch*256 + jcol];
      int kb2 = jcol >> 5, kq2 = (jcol >> 3) & 3, j2 = jcol & 7;
      int rbase = kb2*KBS + kq2*128 + j2;
      #pragma unroll
      for (int mt = 0; mt < 2; ++mt){
        #pragma unroll
        for (int r = 0; r < 4; ++r){
          int tokL = crow0 + r;
          int off = rbase + mt*512 + ((tokL & 12) | ((tokL ^ kq2) & 3))*8;
          float a = fmaxf(acc[nt][mt][r] + bb, 0.f);
          short h = bf16_rn(a);
          Rh[off] = h;
          Rl[off] = bf16_rn(a - bf16_f(h));
        }
      }
    }
    __syncthreads();

    // ---------- GEMM2 partial: counted-vmcnt pipeline (depth-2) ----------
    {
      const short* w2hB = W2h + ch*131072;   // ch*8*16384
      const short* w2lB = W2l + ch*131072;
      const short* qh0 = w2hB + boff2[0];
      const short* ql0 = w2lB + boff2[0];
      const short* qh1 = w2hB + boff2[1];
      const short* ql1 = w2lB + boff2[1];
      const short* qh2 = w2hB + boff2[2];
      const short* ql2 = w2lB + boff2[2];
      const short* qh3 = w2hB + boff2[3];
      const short* ql3 = w2lB + boff2[3];
      bf16x8 Ch[3][4], Cl[3][4];
      #define G2I(S) { Ch[(S)%3][0] = gld16(qh0 + (S)*16384); \
                       Cl[(S)%3][0] = gld16(ql0 + (S)*16384); \
                       Ch[(S)%3][1] = gld16(qh1 + (S)*16384); \
                       Cl[(S)%3][1] = gld16(ql1 + (S)*16384); \
                       Ch[(S)%3][2] = gld16(qh2 + (S)*16384); \
                       Cl[(S)%3][2] = gld16(ql2 + (S)*16384); \
                       Ch[(S)%3][3] = gld16(qh3 + (S)*16384); \
                       Cl[(S)%3][3] = gld16(ql3 + (S)*16384); }
      G2I(0) G2I(1)                      // depth-2 prologue: 16 loads in flight
      #pragma unroll
      for (int kb = 0; kb < 8; ++kb){
        bf16x8 rh0 = *(const bf16x8*)(Rh + kb*KBS + lane_sw);
        bf16x8 rl0 = *(const bf16x8*)(Rl + kb*KBS + lane_sw);
        bf16x8 rh1 = *(const bf16x8*)(Rh + kb*KBS + 512 + lane_sw);
        bf16x8 rl1 = *(const bf16x8*)(Rl + kb*KBS + 512 + lane_sw);
        if (kb < 6) G2I(kb + 2)
        if      (kb < 6)  asm volatile("s_waitcnt vmcnt(16)");
        else if (kb == 6) asm volatile("s_waitcnt vmcnt(8)");
        else              asm volatile("s_waitcnt vmcnt(0)");
        __builtin_amdgcn_sched_barrier(0);
        const int s = kb % 3;            // compile-time (full unroll)
        #pragma unroll
        for (int nt = 0; nt < 4; ++nt){
          ff[nt][0] = __builtin_amdgcn_mfma_f32_16x16x32_bf16(rh0, Ch[s][nt], ff[nt][0], 0,0,0);
          ff[nt][0] = __builtin_amdgcn_mfma_f32_16x16x32_bf16(rl0, Ch[s][nt], ff[nt][0], 0,0,0);
          ff[nt][0] = __builtin_amdgcn_mfma_f32_16x16x32_bf16(rh0, Cl[s][nt], ff[nt][0], 0,0,0);
          ff[nt][1] = __builtin_amdgcn_mfma_f32_16x16x32_bf16(rh1, Ch[s][nt], ff[nt][1], 0,0,0);
          ff[nt][1] = __builtin_amdgcn_mfma_f32_16x16x32_bf16(rl1, Ch[s][nt], ff[nt][1], 0,0,0);
          ff[nt][1] = __builtin_amdgcn_mfma_f32_16x16x32_bf16(rh1, Cl[s][nt], ff[nt][1], 0,0,0);
        }
      }
      #undef G2I
    }
  }

  // ---------------- epilogue (A fully resident: no re-gather) ----------------
  const float G1 = scal[0], BW = scal[1];
  const float* gWg = scal + 2;
  const float bgv  = bg[0];
  const float invT = 1.0f / temp[0];
  int rem  = (tile*32) % 2049;
  int qtok = 2048 - rem;          // valid if < 32

  float ps1[2][4], ps2[2][4], psg[2][4];   // [mt][r]
  #pragma unroll
  for (int mt = 0; mt < 2; ++mt)
    #pragma unroll
    for (int r = 0; r < 4; ++r){ ps1[mt][r]=0.f; ps2[mt][r]=0.f; psg[mt][r]=0.f; }

  #pragma unroll
  for (int nt = 0; nt < 4; ++nt){
    int d = wv*64 + nt*16 + mrow;
    float b2v = b2[d];
    float gw  = gWg[d];
    int kb  = d >> 5, kq2 = (d >> 3) & 3, jj = d & 7;
    int abase = kb*KBS + kq2*128 + jj;
    #pragma unroll
    for (int mt = 0; mt < 2; ++mt){
      #pragma unroll
      for (int r = 0; r < 4; ++r){
        int tokL = crow0 + r;
        int tok  = mt*16 + tokL;
        int off  = abase + mt*512 + ((tokL & 12) | ((tokL ^ kq2) & 3))*8;
        float h = bf16_f(Ah[off]) + bf16_f(Al[off]);
        float x = h + ff[nt][mt][r] + b2v;
        ps1[mt][r] += x;
        ps2[mt][r] = fmaf(x, x, ps2[mt][r]);
        psg[mt][r] = fmaf(x, gw, psg[mt][r]);
        if (tok == qtok) Xq[d] = x;
      }
    }
  }
  // reduce over mrow (lane bits 0..3)
  #pragma unroll
  for (int mt = 0; mt < 2; ++mt){
    #pragma unroll
    for (int r = 0; r < 4; ++r){
      float a = ps1[mt][r], b = ps2[mt][r], c = psg[mt][r];
      #pragma unroll
      for (int m = 1; m < 16; m <<= 1){
        a += __shfl_xor(a, m, 64);
        b += __shfl_xor(b, m, 64);
        c += __shfl_xor(c, m, 64);
      }
      if (mrow == 0){
        int tok = mt*16 + crow0 + r;
        redS1[tok*8 + wv] = a;
        redS2[tok*8 + wv] = b;
        redSG[tok*8 + wv] = c;
      }
    }
  }
  __syncthreads();

  if (t < 32){
    float S1 = 0.f, S2 = 0.f, SG = 0.f;
    #pragma unroll
    for (int w = 0; w < 8; ++w){
      S1 += redS1[t*8 + w];
      S2 += redS2[t*8 + w];
      SG += redSG[t*8 + w];
    }
    float mu  = S1 * (1.f/512.f);
    float var = S2 * (1.f/512.f) - mu*mu;
    float rs  = rsqrtf(var + 1e-5f);
    redMu[t] = mu; redRs[t] = rs;
    int id  = tile*32 + t;
    int b   = id / 2049;
    int pos = id - b*2049;
    if (pos < TCTX){
      float gate = rs*(SG - mu*G1) + BW + bgv;
      float pv = (gate + __builtin_nontemporal_load(gumbel + b*TCTX + pos)) * invT;
      __builtin_nontemporal_store(pv, pert + b*TCTX + pos);
    }
  }
  __syncthreads();

  if (qtok < 32 && t < 256){
    int id = tile*32 + qtok;
    int b  = id / 2049;
    float mu = redMu[qtok], rs = redRs[qtok];
    int d = t*2;
    qh[b*512 + d]     = (Xq[d]  -mu)*rs*gamma[d]   + beta[d];
    qh[b*512 + d + 1] = (Xq[d+1]-mu)*rs*gamma[d+1] + beta[d+1];
  }
}

// ---------------------------------------------------------------- K2: top-3
__global__ __launch_bounds__(256) void k2_topk(const float* __restrict__ pert,
                                               int* __restrict__ idxw){
  __shared__ float v[2048];
  __shared__ float wvv[256];
  __shared__ int   wii[256];
  const int b = blockIdx.x, t = threadIdx.x;
  for (int i = t; i < 2048; i += 256) v[i] = pert[b*TCTX + i];
  __syncthreads();
  for (int r = 0; r < 3; ++r){
    float best = -INFINITY; int bi = 1<<30;
    for (int i = t; i < 2048; i += 256){
      float x = v[i];
      if (x > best || (x == best && i < bi)){ best = x; bi = i; }
    }
    wvv[t] = best; wii[t] = bi;
    __syncthreads();
    for (int s = 128; s > 0; s >>= 1){
      if (t < s){
        float ov = wvv[t+s]; int oi = wii[t+s];
        if (ov > wvv[t] || (ov == wvv[t] && oi < wii[t])){ wvv[t] = ov; wii[t] = oi; }
      }
      __syncthreads();
    }
    if (t == 0){ idxw[b*3 + r] = wii[0]; v[wii[0]] = -INFINITY; }
    __syncthreads();
  }
}

// -------------------------------------- K3: recompute hiddens for top-3 rows
__global__ __launch_bounds__(256) void k3_rows(const int* __restrict__ seq,
    const float* __restrict__ embed, const float* __restrict__ W1, const float* __restrict__ b1,
    const float* __restrict__ W2,    const float* __restrict__ b2,
    const float* __restrict__ gamma, const float* __restrict__ beta,
    const int* __restrict__ idxw, float* __restrict__ memr)
{
  __shared__ float hs[3*512];
  __shared__ float rbuf[3*1024];
  __shared__ float red1[12], red2[12];
  const int t  = threadIdx.x;
  const int b  = blockIdx.x;
  const int wv = t >> 6;
  #pragma unroll
  for (int kk = 0; kk < 3; ++kk){
    int pos = idxw[b*3 + kk];
    int row = seq[b*TFULL + pos];
    ((float2*)(hs + kk*512))[t] = ((const float2*)(embed + row*512))[t];
  }
  __syncthreads();
  const float4* W1v = (const float4*)W1;
  float4 a0 = make_float4(0,0,0,0), a1 = a0, a2 = a0;
  #pragma unroll 2
  for (int d = 0; d < 512; ++d){
    float4 wq = W1v[d*256 + t];
    float h0 = hs[d], h1 = hs[512+d], h2 = hs[1024+d];
    FMA4(a0, h0, wq); FMA4(a1, h1, wq); FMA4(a2, h2, wq);
  }
  float4 bq = ((const float4*)b1)[t];
  float4 r0, r1, r2;
  r0.x = fmaxf(a0.x+bq.x,0.f); r0.y = fmaxf(a0.y+bq.y,0.f);
  r0.z = fmaxf(a0.z+bq.z,0.f); r0.w = fmaxf(a0.w+bq.w,0.f);
  r1.x = fmaxf(a1.x+bq.x,0.f); r1.y = fmaxf(a1.y+bq.y,0.f);
  r1.z = fmaxf(a1.z+bq.z,0.f); r1.w = fmaxf(a1.w+bq.w,0.f);
  r2.x = fmaxf(a2.x+bq.x,0.f); r2.y = fmaxf(a2.y+bq.y,0.f);
  r2.z = fmaxf(a2.z+bq.z,0.f); r2.w = fmaxf(a2.w+bq.w,0.f);
  ((float4*)rbuf)[t]          = r0;
  ((float4*)(rbuf+1024))[t]   = r1;
  ((float4*)(rbuf+2048))[t]   = r2;
  __syncthreads();
  const float2* W2v2 = (const float2*)W2;
  float f0x=0.f,f0y=0.f,f1x=0.f,f1y=0.f,f2x=0.f,f2y=0.f;
  #pragma unroll 2
  for (int j = 0; j < 1024; ++j){
    float2 wq = W2v2[j*256 + t];
    float q0 = rbuf[j], q1 = rbuf[1024+j], q2 = rbuf[2048+j];
    f0x = fmaf(q0, wq.x, f0x); f0y = fmaf(q0, wq.y, f0y);
    f1x = fmaf(q1, wq.x, f1x); f1y = fmaf(q1, wq.y, f1y);
    f2x = fmaf(q2, wq.x, f2x); f2y = fmaf(q2, wq.y, f2y);
  }
  float2 b2q = ((const float2*)b2)[t];
  const int dd = t*2;
  float2 hx0 = ((float2*)hs)[t];
  float2 hx1 = ((float2*)(hs+512))[t];
  float2 hx2 = ((float2*)(hs+1024))[t];
  float x00 = hx0.x + f0x + b2q.x, x01 = hx0.y + f0y + b2q.y;
  float x10 = hx1.x + f1x + b2q.x, x11 = hx1.y + f1y + b2q.y;
  float x20 = hx2.x + f2x + b2q.x, x21 = hx2.y + f2y + b2q.y;
  float s10 = wred64(x00 + x01), s20 = wred64(x00*x00 + x01*x01);
  float s11 = wred64(x10 + x11), s21 = wred64(x10*x10 + x11*x11);
  float s12 = wred64(x20 + x21), s22 = wred64(x20*x20 + x21*x21);
  if ((t & 63) == 0){
    red1[0*4+wv] = s10; red2[0*4+wv] = s20;
    red1[1*4+wv] = s11; red2[1*4+wv] = s21;
    red1[2*4+wv] = s12; red2[2*4+wv] = s22;
  }
  __syncthreads();
  float gx = gamma[dd], gy = gamma[dd+1], bx = beta[dd], by = beta[dd+1];
  #pragma unroll
  for (int kk = 0; kk < 3; ++kk){
    float S1 = red1[kk*4+0]+red1[kk*4+1]+red1[kk*4+2]+red1[kk*4+3];
    float S2 = red2[kk*4+0]+red2[kk*4+1]+red2[kk*4+2]+red2[kk*4+3];
    float mu  = S1*(1.f/512.f);
    float var = S2*(1.f/512.f) - mu*mu;
    float rs  = rsqrtf(var + 1e-5f);
    float x0 = (kk==0) ? x00 : (kk==1) ? x10 : x20;
    float x1 = (kk==0) ? x01 : (kk==1) ? x11 : x21;
    memr[(b*3+kk)*512 + dd]     = (x0-mu)*rs*gx + bx;
    memr[(b*3+kk)*512 + dd + 1] = (x1-mu)*rs*gy + by;
  }
}

// ------------------------------------------- K4: q, slot attention, ctx (T)
__global__ __launch_bounds__(256) void k4_attn(const float* __restrict__ qh,
    const float* __restrict__ Wr, const float* __restrict__ br,
    const float* __restrict__ memr, float* __restrict__ ctxT)
{
  __shared__ float hq[512];
  __shared__ float red[12];
  const int t = threadIdx.x, b = blockIdx.x;
  ((float2*)hq)[t] = ((const float2*)(qh + b*512))[t];
  __syncthreads();
  const float2* Wrv = (const float2*)Wr;
  float qx = 0.f, qy = 0.f;
  #pragma unroll 4
  for (int d = 0; d < 512; ++d){
    float hb = hq[d];
    float2 wq = Wrv[d*256 + t];
    qx = fmaf(hb, wq.x, qx); qy = fmaf(hb, wq.y, qy);
  }
  float2 brq = ((const float2*)br)[t];
  qx += brq.x; qy += brq.y;
  const int dd = t*2;
  const float* m0 = memr + (b*3+0)*512;
  const float* m1 = memr + (b*3+1)*512;
  const float* m2 = memr + (b*3+2)*512;
  float p0 = wred64(qx*m0[dd] + qy*m0[dd+1]);
  float p1 = wred64(qx*m1[dd] + qy*m1[dd+1]);
  float p2 = wred64(qx*m2[dd] + qy*m2[dd+1]);
  if ((t & 63) == 0){ int w = t>>6; red[w*3+0]=p0; red[w*3+1]=p1; red[w*3+2]=p2; }
  __syncthreads();
  float s0 = red[0]+red[3]+red[6]+red[9];
  float s1 = red[1]+red[4]+red[7]+red[10];
  float s2 = red[2]+red[5]+red[8]+red[11];
  float m  = fmaxf(fmaxf(s0, s1), fmaxf(s2, 0.f));
  float e0 = expf(s0-m), e1 = expf(s1-m), e2 = expf(s2-m);
  float den = e0 + e1 + e2 + 13.f*expf(-m);   // 13 empty slots
  float a0 = e0/den, a1 = e1/den, a2 = e2/den;
  float c0 = a0*m0[dd]   + a1*m1[dd]   + a2*m2[dd];
  float c1 = a0*m0[dd+1] + a1*m1[dd+1] + a2*m2[dd+1];
  ctxT[dd*64 + b]     = c0;
  ctxT[(dd+1)*64 + b] = c1;
}

// ----------------------------------------------------- K5: out = ctx@Wo + bo
__global__ __launch_bounds__(256) void k5_out(const float* __restrict__ ctxT,
    const float* __restrict__ Wo, const float* __restrict__ bo,
    float* __restrict__ out)
{
  const int v  = blockIdx.x*256 + threadIdx.x;
  const int vc = v < Vm ? v : Vm-1;
  float acc[64];
  #pragma unroll
  for (int b = 0; b < 64; ++b) acc[b] = 0.f;
  for (int d = 0; d < 512; ++d){
    float w = Wo[d*Vm + vc];
    const float* c = ctxT + d*64;
    #pragma unroll
    for (int b = 0; b < 64; ++b) acc[b] = fmaf(c[b], w, acc[b]);
  }
  if (v < Vm){
    float bb = bo[v];
    #pragma unroll
    for (int b = 0; b < 64; ++b) out[b*Vm + v] = acc[b] + bb;
  }
}

extern "C" void kernel_launch(void* const* d_in, const int* in_sizes, int n_in,
                              void* d_out, int out_size, void* d_ws, size_t ws_size,
                              hipStream_t stream){
  (void)in_sizes; (void)n_in; (void)out_size; (void)ws_size;
  const int*   seq   = (const int*)d_in[0];
  const float* temp  = (const float*)d_in[1];
  const float* gum   = (const float*)d_in[2];
  const float* embed = (const float*)d_in[3];
  const float* W1    = (const float*)d_in[4];
  const float* b1    = (const float*)d_in[5];
  const float* W2    = (const float*)d_in[6];
  const float* b2    = (const float*)d_in[7];
  const float* gamma = (const float*)d_in[8];
  const float* beta  = (const float*)d_in[9];
  const float* Wg    = (const float*)d_in[10];
  const float* bg    = (const float*)d_in[11];
  const float* Wr    = (const float*)d_in[12];
  const float* br    = (const float*)d_in[13];
  const float* Wo    = (const float*)d_in[14];
  const float* bo    = (const float*)d_in[15];
  float* out = (float*)d_out;

  float* wsf  = (float*)d_ws;
  float* pert = wsf;                    // 131072
  float* qh   = wsf + 131072;           // 32768
  float* memr = wsf + 163840;           // 98304
  float* ctxT = wsf + 262144;           // 32768
  float* scal = wsf + 294912;           // 1024 (uses 514)
  int*   idxw = (int*)(wsf + 295936);   // 256 ints
  short* W1h  = (short*)(wsf + 296192); // 512*1024 shorts each plane
  short* W1l  = W1h + 512*1024;
  short* W2h  = W1l + 512*1024;
  short* W2l  = W2h + 1024*512;

  k0_setup<<<1, 512, 0, stream>>>(gamma, beta, Wg, scal);
  kpack<<<256, 256, 0, stream>>>(W1, 1024, 16, W1h, W1l);
  kpack<<<256, 256, 0, stream>>>(W2, 512, 32, W2h, W2l);
  k1_main<<<4098, 512, 0, stream>>>(seq, temp, gum, embed, W1h, W1l, b1,
                                    W2h, W2l, b2, gamma, beta, bg, scal, pert, qh);
  k2_topk<<<64, 256, 0, stream>>>(pert, idxw);
  k3_rows<<<64, 256, 0, stream>>>(seq, embed, W1, b1, W2, b2, gamma, beta, idxw, memr);
  k4_attn<<<64, 256, 0, stream>>>(qh, Wr, br, memr, ctxT);
  k5_out<<<197, 256, 0, stream>>>(ctxT, Wo, bo, out);
}